// Round 5
// baseline (768.831 us; speedup 1.0000x reference)
//
#include <hip/hip_runtime.h>
#include <hip/hip_cooperative_groups.h>

#define NN 50000
#define NE 800000
#define NG 512
#define INDIM 100
#define OUTD 24
#define LROW 72       // padded LDS row (ushorts) for layer tiles
#define XROW 136      // padded LDS row for pre0 x-tile (ushorts)
#define CSR_CAP 64    // fixed csr stride per node; deg~Poisson(16), max~42
// bucket sort params
#define NB 196        // buckets of 256 nodes (d >> 8)
#define BSH 8
#define BCAP 5120
#define CURS 16
#define EPB 4096
// phase work counts
#define NT_PREP 497   // 80 wT + 32 w0T + 1 cursor/tick + 384 gp
#define NT_P1 978     // 196 fillA + 782 pre0
#define NT_LAYER 3125
#define NT_FINAL 128  // 4 graphs per unit

typedef __attribute__((ext_vector_type(8))) short short8;
typedef __attribute__((ext_vector_type(4))) float floatx4;

namespace cg = cooperative_groups;

__device__ inline float bf2f(unsigned short u) {
    unsigned v = (unsigned)u << 16;
    float f;
    __builtin_memcpy(&f, &v, 4);
    return f;
}
__device__ inline unsigned short f2bf(float f) {
    unsigned u;
    __builtin_memcpy(&u, &f, 4);
    u += 0x7fffu + ((u >> 16) & 1u);  // RNE
    return (unsigned short)(u >> 16);
}

struct Params {
    const float* x;
    const int* ei;
    const int* batch;
    const float *w2_0, *w2_1, *w2_2, *w1_1, *w1_2, *w1_0;
    const float *b1_0, *b2_0, *b1_1, *b2_1, *b1_2, *b2_2;
    const float *jkw, *jkb, *fw1, *fb1, *bng, *bnb, *bnm, *bnv, *fw2, *fb2, *ow, *ob;
    float* out;
    unsigned short *ya, *yb;
    float* gp;
    int* count;
    int* csr;
    unsigned short *wT, *w0T;
    int* cursor;
    unsigned* pairs;
    int* tick;
};

// ---------------- phase bodies (verbatim ports of the R4-verified kernels) ----------------

__device__ __forceinline__ void prep_body(const Params& p, int u, int tid) {
    if (u < 80) {
        const float* srcs[5] = {p.w2_0, p.w2_1, p.w2_2, p.w1_1, p.w1_2};
        int id = u >> 4;
        int off = ((u & 15) << 8) + tid;
        int k = off >> 6, n = off & 63;
        p.wT[id * 4096 + n * 64 + k] = f2bf(srcs[id][k * 64 + n]);
    } else if (u < 112) {
        int i = (u - 80) * 256 + tid;
        int n = i >> 7, k = i & 127;
        p.w0T[n * 128 + k] = (k < INDIM) ? f2bf(p.w1_0[k * 64 + n]) : 0;
    } else if (u == 112) {
        for (int i = tid; i < NB * CURS; i += 256) p.cursor[i] = 0;
        if (tid < 4) p.tick[tid] = 0;
    } else {
        int i = (u - 113) * 256 + tid;
        if (i < 3 * NG * 64) p.gp[i] = 0.f;
    }
}

__device__ __forceinline__ void filla_body(const Params& p, int u, int tid, unsigned char* sm) {
    int* lcnt = (int*)sm;
    int* lbase = lcnt + NB;
    for (int i = tid; i < NB; i += 256) lcnt[i] = 0;
    __syncthreads();
    unsigned e0 = (unsigned)u * EPB;
    unsigned short dv[16], sv[16];
    short bkt[16];
#pragma unroll
    for (int j = 0; j < 16; ++j) {
        unsigned e = e0 + j * 256u + tid;
        if (e < NE) {
            int d = p.ei[NE + e];
            int s = p.ei[e];
            dv[j] = (unsigned short)d;
            sv[j] = (unsigned short)s;
            bkt[j] = (short)(d >> BSH);
            atomicAdd(&lcnt[bkt[j]], 1);
        } else {
            bkt[j] = -1;
        }
    }
    __syncthreads();
    for (int i = tid; i < NB; i += 256) {
        lbase[i] = atomicAdd(&p.cursor[i * CURS], lcnt[i]);
        lcnt[i] = 0;
    }
    __syncthreads();
#pragma unroll
    for (int j = 0; j < 16; ++j) {
        if (bkt[j] >= 0) {
            int b = bkt[j];
            int pos = lbase[b] + atomicAdd(&lcnt[b], 1);
            if (pos < BCAP)
                p.pairs[(size_t)b * BCAP + pos] = ((unsigned)dv[j] << 16) | (unsigned)sv[j];
        }
    }
    __syncthreads();  // sm reused by next unit
}

__device__ __forceinline__ void pre0_body(const Params& p, int v, int tid, unsigned char* sm) {
    unsigned short* xs = (unsigned short*)sm;
    int base = v * 64;
    for (int i = tid; i < 64 * 128; i += 256) {
        int r = i >> 7, c = i & 127;
        int node = base + r;
        float val = (c < INDIM && node < NN) ? p.x[(size_t)node * INDIM + c] : 0.f;
        xs[r * XROW + c] = f2bf(val);
    }
    __syncthreads();
    int wave = tid >> 6, lane = tid & 63;
    int quad = lane >> 4, l15 = lane & 15;
#pragma unroll
    for (int nt = 0; nt < 4; ++nt) {
        floatx4 c = {0.f, 0.f, 0.f, 0.f};
#pragma unroll
        for (int kk = 0; kk < 4; ++kk) {
            short8 a = *(const short8*)&xs[(wave * 16 + l15) * XROW + kk * 32 + quad * 8];
            short8 bb = *(const short8*)&p.w0T[(nt * 16 + l15) * 128 + kk * 32 + quad * 8];
            c = __builtin_amdgcn_mfma_f32_16x16x32_bf16(a, bb, c, 0, 0, 0);
        }
        int col = nt * 16 + l15;
#pragma unroll
        for (int r = 0; r < 4; ++r) {
            int row = base + wave * 16 + quad * 4 + r;
            if (row < NN) p.ya[(size_t)row * 64 + col] = f2bf(c[r]);
        }
    }
    __syncthreads();  // sm reused by next unit
}

__device__ __forceinline__ void fillb_body(const Params& p, int b, int tid, unsigned char* sm) {
    int* lcnt = (int*)sm;
    lcnt[tid] = 0;
    __syncthreads();
    int tot = min(p.cursor[b * CURS], BCAP);
    const unsigned* pp = p.pairs + (size_t)b * BCAP;
    for (int i = tid; i < tot; i += 256) {
        unsigned pr = pp[i];
        int d = (int)(pr >> 16);
        int s = (int)(pr & 0xFFFFu);
        int pos = atomicAdd(&lcnt[d & 255], 1);
        if (pos < CSR_CAP) p.csr[(size_t)d * CSR_CAP + pos] = s;
    }
    __syncthreads();
    int node = (b << BSH) + tid;
    if (node < NN) p.count[node] = lcnt[tid];
    __syncthreads();
}

__device__ __forceinline__ void layer_body(const Params& p, int t, int tid,
                                           const unsigned short* __restrict__ y,
                                           const float* __restrict__ b1,
                                           const unsigned short* __restrict__ w2T,
                                           const float* __restrict__ b2,
                                           const unsigned short* __restrict__ wnT,
                                           unsigned short* __restrict__ ynext,
                                           float* __restrict__ gp,
                                           unsigned char* sm) {
    unsigned short* tA = (unsigned short*)sm;
    unsigned short* tB = tA + 16 * LROW;
    int wave = tid >> 6, lane = tid & 63;
    int base = t * 16;
    float bias1 = b1[lane];
    const int* __restrict__ count = p.count;
    const int* __restrict__ csr = p.csr;

    for (int i = 0; i < 4; i += 2) {
        int nA = __builtin_amdgcn_readfirstlane(base + wave * 4 + i);
        int nBn = __builtin_amdgcn_readfirstlane(base + wave * 4 + i + 1);
        int cA = min(count[nA], CSR_CAP);
        int cB = min(count[nBn], CSR_CAP);
        const int* pA = csr + (size_t)nA * CSR_CAP;
        const int* pB = csr + (size_t)nBn * CSR_CAP;
        float aA[4], aB[4];
        aA[0] = bf2f(y[(size_t)nA * 64 + lane]);
        aB[0] = bf2f(y[(size_t)nBn * 64 + lane]);
        aA[1] = aA[2] = aA[3] = 0.f;
        aB[1] = aB[2] = aB[3] = 0.f;
        int eA = 0, eB = 0;
        while (eA + 8 <= cA && eB + 8 <= cB) {
            int iA[8], iB[8];
#pragma unroll
            for (int j = 0; j < 8; ++j) { iA[j] = pA[eA + j]; iB[j] = pB[eB + j]; }
            float vA[8], vB[8];
#pragma unroll
            for (int j = 0; j < 8; ++j) vA[j] = bf2f(y[(size_t)iA[j] * 64 + lane]);
#pragma unroll
            for (int j = 0; j < 8; ++j) vB[j] = bf2f(y[(size_t)iB[j] * 64 + lane]);
#pragma unroll
            for (int j = 0; j < 8; ++j) { aA[j & 3] += vA[j]; aB[j & 3] += vB[j]; }
            eA += 8; eB += 8;
        }
        for (; eA + 8 <= cA; eA += 8) {
            int idx[8];
#pragma unroll
            for (int j = 0; j < 8; ++j) idx[j] = pA[eA + j];
#pragma unroll
            for (int j = 0; j < 8; ++j) aA[j & 3] += bf2f(y[(size_t)idx[j] * 64 + lane]);
        }
        if (eA + 4 <= cA) {
            int i0 = pA[eA], i1 = pA[eA + 1], i2 = pA[eA + 2], i3 = pA[eA + 3];
            aA[0] += bf2f(y[(size_t)i0 * 64 + lane]);
            aA[1] += bf2f(y[(size_t)i1 * 64 + lane]);
            aA[2] += bf2f(y[(size_t)i2 * 64 + lane]);
            aA[3] += bf2f(y[(size_t)i3 * 64 + lane]);
            eA += 4;
        }
        if (eA + 2 <= cA) {
            int i0 = pA[eA], i1 = pA[eA + 1];
            aA[0] += bf2f(y[(size_t)i0 * 64 + lane]);
            aA[1] += bf2f(y[(size_t)i1 * 64 + lane]);
            eA += 2;
        }
        if (eA < cA) aA[0] += bf2f(y[(size_t)pA[eA] * 64 + lane]);
        for (; eB + 8 <= cB; eB += 8) {
            int idx[8];
#pragma unroll
            for (int j = 0; j < 8; ++j) idx[j] = pB[eB + j];
#pragma unroll
            for (int j = 0; j < 8; ++j) aB[j & 3] += bf2f(y[(size_t)idx[j] * 64 + lane]);
        }
        if (eB + 4 <= cB) {
            int i0 = pB[eB], i1 = pB[eB + 1], i2 = pB[eB + 2], i3 = pB[eB + 3];
            aB[0] += bf2f(y[(size_t)i0 * 64 + lane]);
            aB[1] += bf2f(y[(size_t)i1 * 64 + lane]);
            aB[2] += bf2f(y[(size_t)i2 * 64 + lane]);
            aB[3] += bf2f(y[(size_t)i3 * 64 + lane]);
            eB += 4;
        }
        if (eB + 2 <= cB) {
            int i0 = pB[eB], i1 = pB[eB + 1];
            aB[0] += bf2f(y[(size_t)i0 * 64 + lane]);
            aB[1] += bf2f(y[(size_t)i1 * 64 + lane]);
            eB += 2;
        }
        if (eB < cB) aB[0] += bf2f(y[(size_t)pB[eB] * 64 + lane]);

        float sA = (aA[0] + aA[1]) + (aA[2] + aA[3]);
        float sB = (aB[0] + aB[1]) + (aB[2] + aB[3]);
        tA[(wave * 4 + i) * LROW + lane]     = f2bf(fmaxf(sA + bias1, 0.f));
        tA[(wave * 4 + i + 1) * LROW + lane] = f2bf(fmaxf(sB + bias1, 0.f));
    }
    __syncthreads();

    int quad = lane >> 4, l15 = lane & 15;

    // GEMM1: h = relu(t @ w2 + b2) -> tB
    short8 a_k0 = *(const short8*)&tA[l15 * LROW + quad * 8];
    short8 a_k1 = *(const short8*)&tA[l15 * LROW + 32 + quad * 8];
    {
        int col = wave * 16 + l15;
        short8 b_k0 = *(const short8*)&w2T[col * 64 + quad * 8];
        short8 b_k1 = *(const short8*)&w2T[col * 64 + 32 + quad * 8];
        floatx4 c = {0.f, 0.f, 0.f, 0.f};
        c = __builtin_amdgcn_mfma_f32_16x16x32_bf16(a_k0, b_k0, c, 0, 0, 0);
        c = __builtin_amdgcn_mfma_f32_16x16x32_bf16(a_k1, b_k1, c, 0, 0, 0);
        float bb = b2[col];
#pragma unroll
        for (int r = 0; r < 4; ++r) {
            float h = fmaxf(c[r] + bb, 0.f);
            tB[(quad * 4 + r) * LROW + col] = f2bf(h);
        }
    }
    __syncthreads();

    // block-level segmented pool
    if (wave == 0) {
        float run = 0.f;
        int curg = p.batch[base];
        for (int r = 0; r < 16; ++r) {
            int g2 = p.batch[base + r];
            if (g2 != curg) {
                atomicAdd(&gp[curg * 64 + lane], run);
                run = 0.f;
                curg = g2;
            }
            run += bf2f(tB[r * LROW + lane]);
        }
        atomicAdd(&gp[curg * 64 + lane], run);
    }

    if (ynext) {
        short8 h_k0 = *(const short8*)&tB[l15 * LROW + quad * 8];
        short8 h_k1 = *(const short8*)&tB[l15 * LROW + 32 + quad * 8];
        int col = wave * 16 + l15;
        short8 w_k0 = *(const short8*)&wnT[col * 64 + quad * 8];
        short8 w_k1 = *(const short8*)&wnT[col * 64 + 32 + quad * 8];
        floatx4 cy = {0.f, 0.f, 0.f, 0.f};
        cy = __builtin_amdgcn_mfma_f32_16x16x32_bf16(h_k0, w_k0, cy, 0, 0, 0);
        cy = __builtin_amdgcn_mfma_f32_16x16x32_bf16(h_k1, w_k1, cy, 0, 0, 0);
#pragma unroll
        for (int r = 0; r < 4; ++r) {
            int row = base + quad * 4 + r;
            ynext[(size_t)row * 64 + col] = f2bf(cy[r]);
        }
    }
    __syncthreads();  // sm (tA/tB) reused by next tile
}

__device__ inline int lbound(const int* __restrict__ b, int v) {
    int lo = 0, hi = NN;
    while (lo < hi) {
        int m = (lo + hi) >> 1;
        if (b[m] < v) lo = m + 1; else hi = m;
    }
    return lo;
}

__device__ __forceinline__ void final_body(const Params& p, int u, int tid, unsigned char* sm) {
    int wave = tid >> 6, lane = tid & 63;
    int gr = u * 4 + wave;
    float* gs = (float*)sm + wave * 384;
    float* gv = gs + 192;
    float* t2 = gv + 64;
    float* t3 = t2 + 64;
    gs[lane]       = p.gp[0 * NG * 64 + gr * 64 + lane];
    gs[64 + lane]  = p.gp[1 * NG * 64 + gr * 64 + lane];
    gs[128 + lane] = p.gp[2 * NG * 64 + gr * 64 + lane];
    float cntf = (float)(lbound(p.batch, gr + 1) - lbound(p.batch, gr));
    __syncthreads();
    float acc = cntf * p.jkb[lane];
#pragma unroll 8
    for (int k = 0; k < 192; ++k) acc = fmaf(gs[k], p.jkw[k * 64 + lane], acc);
    gv[lane] = acc;
    __syncthreads();
    acc = p.fb1[lane];
#pragma unroll 8
    for (int k = 0; k < 64; ++k) acc = fmaf(gv[k], p.fw1[k * 64 + lane], acc);
    acc = (acc - p.bnm[lane]) * rsqrtf(p.bnv[lane] + 1e-5f) * p.bng[lane] + p.bnb[lane];
    t2[lane] = fmaxf(acc, 0.f);
    __syncthreads();
    float acc2 = p.fb2[lane];
#pragma unroll 8
    for (int k = 0; k < 64; ++k) acc2 = fmaf(t2[k], p.fw2[k * 64 + lane], acc2);
    t3[lane] = acc2;
    __syncthreads();
    if (lane < OUTD) {
        float acc3 = p.ob[lane];
#pragma unroll 8
        for (int k = 0; k < 64; ++k) acc3 = fmaf(t3[k], p.ow[k * OUTD + lane], acc3);
        p.out[gr * OUTD + lane] = acc3;
    }
}

// ---------------- the single cooperative kernel ----------------

__global__ __launch_bounds__(256) void k_all(Params p) {
    cg::grid_group grid = cg::this_grid();
    __shared__ __align__(16) unsigned char sm[64 * XROW * 2];  // 17408B, max over phases
    __shared__ int sT;
    int tid = threadIdx.x;
    int nb = gridDim.x;
    int bid = blockIdx.x;

    // phase 0: prep (weight transposes, zero cursor/tickets/gp)
    for (int u = bid; u < NT_PREP; u += nb) prep_body(p, u, tid);
    grid.sync();

    // phase 1: fillA | pre0 (static first unit + ticketed extras)
    {
        if (bid < NT_P1) {
            if (bid < NB) filla_body(p, bid, tid, sm);
            else pre0_body(p, bid - NB, tid, sm);
        }
        if (nb < NT_P1) {
            for (;;) {
                __syncthreads();
                if (tid == 0) sT = nb + atomicAdd(&p.tick[0], 1);
                __syncthreads();
                int t2 = sT;
                if (t2 >= NT_P1) break;
                if (t2 < NB) filla_body(p, t2, tid, sm);
                else pre0_body(p, t2 - NB, tid, sm);
            }
        }
    }
    grid.sync();

    // phase 2: fillB (per-bucket CSR fill, LDS atomics)
    for (int u = bid; u < NB; u += nb) fillb_body(p, u, tid, sm);
    grid.sync();

    // phases 3-5: the three GIN layers
#pragma unroll 1
    for (int l = 0; l < 3; ++l) {
        const unsigned short* yin = (l == 1) ? p.yb : p.ya;
        unsigned short* yout = (l == 0) ? p.yb : ((l == 1) ? p.ya : nullptr);
        const unsigned short* w2T = p.wT + l * 4096;
        const unsigned short* wnT = p.wT + (3 + l) * 4096;
        const float* b1 = (l == 0) ? p.b1_0 : (l == 1) ? p.b1_1 : p.b1_2;
        const float* b2 = (l == 0) ? p.b2_0 : (l == 1) ? p.b2_1 : p.b2_2;
        float* gp = p.gp + l * NG * 64;
        if (bid < NT_LAYER)
            layer_body(p, bid, tid, yin, b1, w2T, b2, wnT, yout, gp, sm);
        for (;;) {
            __syncthreads();
            if (tid == 0) sT = nb + atomicAdd(&p.tick[1 + l], 1);
            __syncthreads();
            int t2 = sT;
            if (t2 >= NT_LAYER) break;
            layer_body(p, t2, tid, yin, b1, w2T, b2, wnT, yout, gp, sm);
        }
        grid.sync();
    }

    // phase 6: final head (4 graphs per block-unit)
    if (bid < NT_FINAL) final_body(p, bid, tid, sm);
}

extern "C" void kernel_launch(void* const* d_in, const int* in_sizes, int n_in,
                              void* d_out, int out_size, void* d_ws, size_t ws_size,
                              hipStream_t stream) {
    Params p;
    p.x     = (const float*)d_in[0];
    p.ei    = (const int*)d_in[1];
    p.batch = (const int*)d_in[2];
    p.w1_0 = (const float*)d_in[3];
    p.b1_0 = (const float*)d_in[4];
    p.w2_0 = (const float*)d_in[5];
    p.b2_0 = (const float*)d_in[6];
    p.w1_1 = (const float*)d_in[7];
    p.b1_1 = (const float*)d_in[8];
    p.w2_1 = (const float*)d_in[9];
    p.b2_1 = (const float*)d_in[10];
    p.w1_2 = (const float*)d_in[11];
    p.b1_2 = (const float*)d_in[12];
    p.w2_2 = (const float*)d_in[13];
    p.b2_2 = (const float*)d_in[14];
    p.jkw  = (const float*)d_in[15];
    p.jkb  = (const float*)d_in[16];
    p.fw1  = (const float*)d_in[17];
    p.fb1  = (const float*)d_in[18];
    p.bng  = (const float*)d_in[19];
    p.bnb  = (const float*)d_in[20];
    p.bnm  = (const float*)d_in[21];
    p.bnv  = (const float*)d_in[22];
    p.fw2  = (const float*)d_in[23];
    p.fb2  = (const float*)d_in[24];
    p.ow   = (const float*)d_in[25];
    p.ob   = (const float*)d_in[26];
    p.out  = (float*)d_out;

    // workspace layout
    float* ws = (float*)d_ws;
    p.ya = (unsigned short*)ws;                              // 3.2M bf16
    p.yb = p.ya + 3200000;                                   // 3.2M bf16
    p.gp = (float*)(p.yb + 3200000);                         // 3 x NG x 64 fp32
    p.count = (int*)(p.gp + 3 * NG * 64);                    // 50000
    p.csr = p.count + NN;                                    // NN * CSR_CAP ints
    p.wT = (unsigned short*)(p.csr + (size_t)NN * CSR_CAP);  // 5 x 4096 bf16
    p.w0T = p.wT + 5 * 4096;                                 // 64 x 128 bf16
    p.cursor = (int*)(p.w0T + 64 * 128);                     // NB*CURS ints
    p.pairs = (unsigned*)(p.cursor + NB * CURS);             // NB * BCAP u32
    p.tick = (int*)(p.pairs + (size_t)NB * BCAP);            // 4 ints

    // grid sized to guaranteed co-residency (computed once)
    static int nblk_s = 0;
    if (nblk_s == 0) {
        int dev = 0;
        hipGetDevice(&dev);
        hipDeviceProp_t prop;
        hipGetDeviceProperties(&prop, dev);
        int mb = 0;
        hipOccupancyMaxActiveBlocksPerMultiprocessor(&mb, reinterpret_cast<const void*>(k_all), 256, 0);
        if (mb < 1) mb = 1;
        long nb = (long)mb * prop.multiProcessorCount;
        if (nb > 2048) nb = 2048;
        if (nb < 256) nb = 256;
        nblk_s = (int)nb;
    }

    void* args[] = { (void*)&p };
    hipLaunchCooperativeKernel(reinterpret_cast<void*>(k_all),
                               dim3(nblk_s), dim3(256), args, 0, stream);
}

// Round 6
// 276.081 us; speedup vs baseline: 2.7848x; 2.7848x over previous
//
#include <hip/hip_runtime.h>

#define NN 50000
#define NE 800000
#define NG 512
#define INDIM 100
#define OUTD 24
#define LROW 72       // padded LDS row (ushorts): 144B stride, 16B-aligned
#define XROW 136      // padded LDS row for pre0 x-tile (ushorts)
#define CSR_CAP 64    // fixed csr stride per node; deg~Poisson(16), max~42
#define YSZ 3200064   // (NN+1) rows of 64 bf16: +1 zeroed dummy row for gather tails
// bucket sort params
#define NB 196        // buckets of 256 nodes (d >> 8), 196*256 = 50176 >= NN
#define BSH 8
#define BCAP 5120     // pairs capacity per bucket (expected 4096, +16 sigma)
#define CURS 16       // cursor padding stride (ints) -> 1 cursor per 64B line
#define EPB 4096      // edges per pass-A block
// k_prep block-role boundaries
#define B_WPREP 80
#define B_WPREP0 112   // +32
#define B_CNT0 308     // +196 (zero count[50000] + cursor + dummy rows)
#define B_GP0 692      // +384 (zero gp[3*NG*64])

typedef __attribute__((ext_vector_type(8))) short short8;
typedef __attribute__((ext_vector_type(4))) float floatx4;

// bf16 raw-bits helpers (RNE pack)
__device__ inline float bf2f(unsigned short u) {
    unsigned v = (unsigned)u << 16;
    float f;
    __builtin_memcpy(&f, &v, 4);
    return f;
}
__device__ inline unsigned short f2bf(float f) {
    unsigned u;
    __builtin_memcpy(&u, &f, 4);
    u += 0x7fffu + ((u >> 16) & 1u);  // round-to-nearest-even
    return (unsigned short)(u >> 16);
}

// ---------------- prep: weight transposes + buffer zeroing, one dispatch ----------------

__global__ __launch_bounds__(256) void k_prep(const float* __restrict__ s0, const float* __restrict__ s1,
                                              const float* __restrict__ s2, const float* __restrict__ s3,
                                              const float* __restrict__ s4,
                                              const float* __restrict__ w1_0,
                                              unsigned short* __restrict__ wT,
                                              unsigned short* __restrict__ w0T,
                                              int* __restrict__ count,
                                              float* __restrict__ gp,
                                              int* __restrict__ cursor,
                                              unsigned short* __restrict__ ya,
                                              unsigned short* __restrict__ yb) {
    int b = blockIdx.x, tid = threadIdx.x;
    if (b < B_WPREP) {
        const float* srcs[5] = {s0, s1, s2, s3, s4};
        int id = b >> 4;
        int off = ((b & 15) << 8) + tid;
        int k = off >> 6, n = off & 63;
        wT[id * 4096 + n * 64 + k] = f2bf(srcs[id][k * 64 + n]);
    } else if (b < B_WPREP0) {
        int i = (b - B_WPREP) * 256 + tid;
        int n = i >> 7, k = i & 127;
        w0T[n * 128 + k] = (k < INDIM) ? f2bf(w1_0[k * 64 + n]) : 0;
    } else if (b < B_CNT0) {
        int i = (b - B_WPREP0) * 256 + tid;
        if (i < NN) count[i] = 0;
        if (i < NB * CURS) cursor[i] = 0;
        if (i < 64) {  // zero dummy gather row in both ping-pong buffers
            ya[(size_t)NN * 64 + i] = 0;
            yb[(size_t)NN * 64 + i] = 0;
        }
    } else {
        int i = (b - B_CNT0) * 256 + tid;
        if (i < 3 * NG * 64) gp[i] = 0.f;
    }
}

// ---------------- CSR build pass A: bucket the edges (R4-verified) ----------------

__global__ __launch_bounds__(256) void k_fill_a(const int* __restrict__ ei,
                                                int* __restrict__ cursor,
                                                unsigned* __restrict__ pairs) {
    __shared__ int lcnt[NB];
    __shared__ int lbase[NB];
    int t = threadIdx.x;
    for (int i = t; i < NB; i += 256) lcnt[i] = 0;
    __syncthreads();
    unsigned e0 = blockIdx.x * EPB;
    unsigned short dv[16], sv[16];
    short bkt[16];
#pragma unroll
    for (int j = 0; j < 16; ++j) {
        unsigned e = e0 + j * 256u + t;
        if (e < NE) {
            int d = ei[NE + e];
            int s = ei[e];
            dv[j] = (unsigned short)d;
            sv[j] = (unsigned short)s;  // node ids < 50000 < 65536
            bkt[j] = (short)(d >> BSH);
            atomicAdd(&lcnt[bkt[j]], 1);
        } else {
            bkt[j] = -1;
        }
    }
    __syncthreads();
    for (int i = t; i < NB; i += 256) {
        lbase[i] = atomicAdd(&cursor[i * CURS], lcnt[i]);
        lcnt[i] = 0;
    }
    __syncthreads();
#pragma unroll
    for (int j = 0; j < 16; ++j) {
        if (bkt[j] >= 0) {
            int b = bkt[j];
            int p = lbase[b] + atomicAdd(&lcnt[b], 1);
            if (p < BCAP)
                pairs[(size_t)b * BCAP + p] = ((unsigned)dv[j] << 16) | (unsigned)sv[j];
        }
    }
}

// ---------------- merged: CSR pass B (buckets) | y0 MFMA (independent roles) ----------------

__global__ __launch_bounds__(256) void k_mid2(const unsigned* __restrict__ pairs,
                                              const int* __restrict__ cursor,
                                              int* __restrict__ count,
                                              int* __restrict__ csr,
                                              const float* __restrict__ x,
                                              const unsigned short* __restrict__ w1T,  // [64][128] bf16
                                              unsigned short* __restrict__ y) {
    __shared__ __align__(16) unsigned short xs[64 * XROW];  // pre0 tile; fillB reuses as lcnt
    int tid = threadIdx.x;
    if (blockIdx.x < NB) {
        // ---- fillB: per-bucket CSR fill, LDS atomics only ----
        int* lcnt = (int*)xs;
        int b = blockIdx.x;
        lcnt[tid] = 0;
        __syncthreads();
        int tot = min(cursor[b * CURS], BCAP);
        const unsigned* pp = pairs + (size_t)b * BCAP;
        for (int i = tid; i < tot; i += 256) {
            unsigned pr = pp[i];
            int d = (int)(pr >> 16);
            int s = (int)(pr & 0xFFFFu);
            int pos = atomicAdd(&lcnt[d & 255], 1);
            if (pos < CSR_CAP) csr[(size_t)d * CSR_CAP + pos] = s;
        }
        __syncthreads();
        int node = (b << BSH) + tid;
        if (node < NN) count[node] = lcnt[tid];
        return;
    }
    // ---- pre0 GEMM ----
    int base = (blockIdx.x - NB) * 64;
    for (int i = tid; i < 64 * 128; i += 256) {
        int r = i >> 7, c = i & 127;
        int node = base + r;
        float v = (c < INDIM && node < NN) ? x[(size_t)node * INDIM + c] : 0.f;
        xs[r * XROW + c] = f2bf(v);
    }
    __syncthreads();
    int wave = tid >> 6, lane = tid & 63;
    int quad = lane >> 4, l15 = lane & 15;
#pragma unroll
    for (int nt = 0; nt < 4; ++nt) {
        floatx4 c = {0.f, 0.f, 0.f, 0.f};
#pragma unroll
        for (int kk = 0; kk < 4; ++kk) {
            short8 a = *(const short8*)&xs[(wave * 16 + l15) * XROW + kk * 32 + quad * 8];
            short8 bb = *(const short8*)&w1T[(nt * 16 + l15) * 128 + kk * 32 + quad * 8];
            c = __builtin_amdgcn_mfma_f32_16x16x32_bf16(a, bb, c, 0, 0, 0);
        }
        int col = nt * 16 + l15;
#pragma unroll
        for (int r = 0; r < 4; ++r) {
            int row = base + wave * 16 + quad * 4 + r;
            if (row < NN) y[(size_t)row * 64 + col] = f2bf(c[r]);
        }
    }
}

// ---------------- fused layer: 4-way interleaved gather (32 rows in flight / wave) ----------------
// Theory: R1 (narrow) and R2 (wide) gathers both held ~16 rows in flight per wave and timed
// identically -> gather is concurrency-limited. 4-node interleave doubles rows in flight.
// Tail edges read zeroed dummy row y[NN] via scalar select; summation order matches R4 exactly.

template <bool HAS_NEXT>
__global__ __launch_bounds__(256) void k_layer(const unsigned short* __restrict__ y,
                                               const int* __restrict__ count,
                                               const int* __restrict__ csr,
                                               const float* __restrict__ b1,
                                               const unsigned short* __restrict__ w2T,  // bf16 [n][k]
                                               const float* __restrict__ b2,
                                               const unsigned short* __restrict__ wnT,  // bf16 [n][k]
                                               unsigned short* __restrict__ ynext,
                                               const int* __restrict__ batch,
                                               float* __restrict__ gp) {
    __shared__ __align__(16) unsigned short tA[16 * LROW];
    __shared__ __align__(16) unsigned short tB[16 * LROW];
    int wave = threadIdx.x >> 6, lane = threadIdx.x & 63;
    int base = blockIdx.x * 16;  // NN = 3125 * 16 exactly
    float bias1 = b1[lane];

    {
        int nk0 = __builtin_amdgcn_readfirstlane(base + wave * 4 + 0);
        int nk1 = __builtin_amdgcn_readfirstlane(base + wave * 4 + 1);
        int nk2 = __builtin_amdgcn_readfirstlane(base + wave * 4 + 2);
        int nk3 = __builtin_amdgcn_readfirstlane(base + wave * 4 + 3);
        int ck0 = min(count[nk0], CSR_CAP);
        int ck1 = min(count[nk1], CSR_CAP);
        int ck2 = min(count[nk2], CSR_CAP);
        int ck3 = min(count[nk3], CSR_CAP);
        const int* pk0 = csr + (size_t)nk0 * CSR_CAP;
        const int* pk1 = csr + (size_t)nk1 * CSR_CAP;
        const int* pk2 = csr + (size_t)nk2 * CSR_CAP;
        const int* pk3 = csr + (size_t)nk3 * CSR_CAP;

        float a0[4], a1[4], a2[4], a3[4];
        a0[0] = bf2f(y[(size_t)nk0 * 64 + lane]);
        a1[0] = bf2f(y[(size_t)nk1 * 64 + lane]);
        a2[0] = bf2f(y[(size_t)nk2 * 64 + lane]);
        a3[0] = bf2f(y[(size_t)nk3 * 64 + lane]);
        a0[1] = a0[2] = a0[3] = 0.f;
        a1[1] = a1[2] = a1[3] = 0.f;
        a2[1] = a2[2] = a2[3] = 0.f;
        a3[1] = a3[2] = a3[3] = 0.f;

        int cmax = max(max(ck0, ck1), max(ck2, ck3));
        int np = (cmax + 7) >> 3;
        for (int t = 0; t < np; ++t) {
            int e = t * 8;
            // issue all 4 nodes' batches before consuming (32 rows in flight)
            unsigned short r0[8], r1[8], r2[8], r3[8];
            int v0 = e < ck0, v1 = e < ck1, v2 = e < ck2, v3 = e < ck3;
#pragma unroll
            for (int j = 0; j < 8; ++j) {
                int i0 = (v0 && e + j < ck0) ? pk0[e + j] : NN;
                r0[j] = y[(size_t)i0 * 64 + lane];
            }
#pragma unroll
            for (int j = 0; j < 8; ++j) {
                int i1 = (v1 && e + j < ck1) ? pk1[e + j] : NN;
                r1[j] = y[(size_t)i1 * 64 + lane];
            }
#pragma unroll
            for (int j = 0; j < 8; ++j) {
                int i2 = (v2 && e + j < ck2) ? pk2[e + j] : NN;
                r2[j] = y[(size_t)i2 * 64 + lane];
            }
#pragma unroll
            for (int j = 0; j < 8; ++j) {
                int i3 = (v3 && e + j < ck3) ? pk3[e + j] : NN;
                r3[j] = y[(size_t)i3 * 64 + lane];
            }
#pragma unroll
            for (int j = 0; j < 8; ++j) {
                a0[j & 3] += bf2f(r0[j]);
                a1[j & 3] += bf2f(r1[j]);
                a2[j & 3] += bf2f(r2[j]);
                a3[j & 3] += bf2f(r3[j]);
            }
        }

        float s0 = (a0[0] + a0[1]) + (a0[2] + a0[3]);
        float s1 = (a1[0] + a1[1]) + (a1[2] + a1[3]);
        float s2 = (a2[0] + a2[1]) + (a2[2] + a2[3]);
        float s3 = (a3[0] + a3[1]) + (a3[2] + a3[3]);
        tA[(wave * 4 + 0) * LROW + lane] = f2bf(fmaxf(s0 + bias1, 0.f));
        tA[(wave * 4 + 1) * LROW + lane] = f2bf(fmaxf(s1 + bias1, 0.f));
        tA[(wave * 4 + 2) * LROW + lane] = f2bf(fmaxf(s2 + bias1, 0.f));
        tA[(wave * 4 + 3) * LROW + lane] = f2bf(fmaxf(s3 + bias1, 0.f));
    }
    __syncthreads();

    int quad = lane >> 4, l15 = lane & 15;

    // ---- GEMM1: h = relu(t @ w2 + b2) -> tB; 4 n-tiles, 1 per wave ----
    short8 a_k0 = *(const short8*)&tA[l15 * LROW + quad * 8];
    short8 a_k1 = *(const short8*)&tA[l15 * LROW + 32 + quad * 8];
    {
        int col = wave * 16 + l15;
        short8 b_k0 = *(const short8*)&w2T[col * 64 + quad * 8];
        short8 b_k1 = *(const short8*)&w2T[col * 64 + 32 + quad * 8];
        floatx4 c = {0.f, 0.f, 0.f, 0.f};
        c = __builtin_amdgcn_mfma_f32_16x16x32_bf16(a_k0, b_k0, c, 0, 0, 0);
        c = __builtin_amdgcn_mfma_f32_16x16x32_bf16(a_k1, b_k1, c, 0, 0, 0);
        float bb = b2[col];
#pragma unroll
        for (int r = 0; r < 4; ++r) {
            float h = fmaxf(c[r] + bb, 0.f);  // inter-layer ReLU
            tB[(quad * 4 + r) * LROW + col] = f2bf(h);
        }
    }
    __syncthreads();

    // ---- block-level segmented pool: wave 0 scans 16 rows ----
    if (wave == 0) {
        float run = 0.f;
        int curg = batch[base];
        for (int r = 0; r < 16; ++r) {
            int g2 = batch[base + r];
            if (g2 != curg) {
                atomicAdd(&gp[curg * 64 + lane], run);
                run = 0.f;
                curg = g2;
            }
            run += bf2f(tB[r * LROW + lane]);
        }
        atomicAdd(&gp[curg * 64 + lane], run);
    }

    if (HAS_NEXT) {
        // ---- GEMM3: yn = h @ wnext; 1 n-tile per wave ----
        short8 h_k0 = *(const short8*)&tB[l15 * LROW + quad * 8];
        short8 h_k1 = *(const short8*)&tB[l15 * LROW + 32 + quad * 8];
        int col = wave * 16 + l15;
        short8 w_k0 = *(const short8*)&wnT[col * 64 + quad * 8];
        short8 w_k1 = *(const short8*)&wnT[col * 64 + 32 + quad * 8];
        floatx4 cy = {0.f, 0.f, 0.f, 0.f};
        cy = __builtin_amdgcn_mfma_f32_16x16x32_bf16(h_k0, w_k0, cy, 0, 0, 0);
        cy = __builtin_amdgcn_mfma_f32_16x16x32_bf16(h_k1, w_k1, cy, 0, 0, 0);
#pragma unroll
        for (int r = 0; r < 4; ++r) {
            int row = base + quad * 4 + r;
            ynext[(size_t)row * 64 + col] = f2bf(cy[r]);
        }
    }
}

// ---------------- final head: pooled-JK + ffn + out; graph size via binary search ----------------

__device__ inline int lbound(const int* __restrict__ b, int v) {
    int lo = 0, hi = NN;
    while (lo < hi) {
        int m = (lo + hi) >> 1;
        if (b[m] < v) lo = m + 1; else hi = m;
    }
    return lo;
}

__global__ __launch_bounds__(64) void k_final(const float* __restrict__ gp,   // [3][NG][64]
                                              const int* __restrict__ batch,  // sorted
                                              const float* __restrict__ jkw,  // fp32 [192][64]
                                              const float* __restrict__ jkb,
                                              const float* __restrict__ w1,
                                              const float* __restrict__ b1,
                                              const float* __restrict__ bng,
                                              const float* __restrict__ bnb,
                                              const float* __restrict__ bnm,
                                              const float* __restrict__ bnv,
                                              const float* __restrict__ w2,
                                              const float* __restrict__ b2,
                                              const float* __restrict__ ow,
                                              const float* __restrict__ ob,
                                              float* __restrict__ out) {
    __shared__ float gs[192];
    __shared__ float gv[64];
    __shared__ float t2[64];
    __shared__ float t3[64];
    int gr = blockIdx.x, lane = threadIdx.x;
    gs[lane]       = gp[0 * NG * 64 + gr * 64 + lane];
    gs[64 + lane]  = gp[1 * NG * 64 + gr * 64 + lane];
    gs[128 + lane] = gp[2 * NG * 64 + gr * 64 + lane];
    float cntf = (float)(lbound(batch, gr + 1) - lbound(batch, gr));
    __syncthreads();
    float acc = cntf * jkb[lane];
#pragma unroll 8
    for (int k = 0; k < 192; ++k) acc = fmaf(gs[k], jkw[k * 64 + lane], acc);
    gv[lane] = acc;
    __syncthreads();
    acc = b1[lane];
#pragma unroll 8
    for (int k = 0; k < 64; ++k) acc = fmaf(gv[k], w1[k * 64 + lane], acc);
    acc = (acc - bnm[lane]) * rsqrtf(bnv[lane] + 1e-5f) * bng[lane] + bnb[lane];
    t2[lane] = fmaxf(acc, 0.f);
    __syncthreads();
    float acc2 = b2[lane];
#pragma unroll 8
    for (int k = 0; k < 64; ++k) acc2 = fmaf(t2[k], w2[k * 64 + lane], acc2);
    t3[lane] = acc2;
    __syncthreads();
    if (lane < OUTD) {
        float acc3 = ob[lane];
#pragma unroll 8
        for (int k = 0; k < 64; ++k) acc3 = fmaf(t3[k], ow[k * OUTD + lane], acc3);
        out[gr * OUTD + lane] = acc3;
    }
}

extern "C" void kernel_launch(void* const* d_in, const int* in_sizes, int n_in,
                              void* d_out, int out_size, void* d_ws, size_t ws_size,
                              hipStream_t stream) {
    const float* x     = (const float*)d_in[0];
    const int*   ei    = (const int*)d_in[1];
    const int*   batch = (const int*)d_in[2];
    const float* w1_0 = (const float*)d_in[3];
    const float* b1_0 = (const float*)d_in[4];
    const float* w2_0 = (const float*)d_in[5];
    const float* b2_0 = (const float*)d_in[6];
    const float* w1_1 = (const float*)d_in[7];
    const float* b1_1 = (const float*)d_in[8];
    const float* w2_1 = (const float*)d_in[9];
    const float* b2_1 = (const float*)d_in[10];
    const float* w1_2 = (const float*)d_in[11];
    const float* b1_2 = (const float*)d_in[12];
    const float* w2_2 = (const float*)d_in[13];
    const float* b2_2 = (const float*)d_in[14];
    const float* jk_w = (const float*)d_in[15];
    const float* jk_b = (const float*)d_in[16];
    const float* ffn_w1 = (const float*)d_in[17];
    const float* ffn_b1 = (const float*)d_in[18];
    const float* bn_g = (const float*)d_in[19];
    const float* bn_b = (const float*)d_in[20];
    const float* bn_m = (const float*)d_in[21];
    const float* bn_v = (const float*)d_in[22];
    const float* ffn_w2 = (const float*)d_in[23];
    const float* ffn_b2 = (const float*)d_in[24];
    const float* out_w  = (const float*)d_in[25];
    const float* out_b  = (const float*)d_in[26];

    // workspace layout
    float* ws = (float*)d_ws;
    unsigned short* ya = (unsigned short*)ws;          // (NN+1) x 64 bf16 (dummy row)
    unsigned short* yb = ya + YSZ;
    float* gp  = (float*)(yb + YSZ);                   // 3 x NG x 64 fp32
    int*   count = (int*)(gp + 3 * NG * 64);           // 50000
    int*   csr   = count + NN;                         // NN * CSR_CAP ints = 12.8MB
    unsigned short* wT  = (unsigned short*)(csr + (size_t)NN * CSR_CAP);  // 5 x 4096 bf16
    unsigned short* w0T = wT + 5 * 4096;                                  // 64 x 128 bf16
    int* cursor = (int*)(w0T + 64 * 128);                                 // NB*CURS ints
    unsigned* pairs = (unsigned*)(cursor + NB * CURS);                    // NB * BCAP u32

    // ---- prep: weight transposes + zero count/cursor/gp/dummy (one dispatch) ----
    k_prep<<<B_GP0, 256, 0, stream>>>(w2_0, w2_1, w2_2, w1_1, w1_2, w1_0,
                                      wT, w0T, count, gp, cursor, ya, yb);

    // ---- CSR pass A ----
    k_fill_a<<<(NE + EPB - 1) / EPB, 256, 0, stream>>>(ei, cursor, pairs);

    // ---- merged: CSR pass B | y0 MFMA (independent roles, one dispatch) ----
    k_mid2<<<NB + (NN + 63) / 64, 256, 0, stream>>>(pairs, cursor, count, csr, x, w0T, ya);

    int nblk = NN / 16;  // 3125, exact
    // ---- layer 0 ----
    k_layer<true><<<nblk, 256, 0, stream>>>(ya, count, csr, b1_0,
                                            wT + 0 * 4096, b2_0, wT + 3 * 4096,
                                            yb, batch, gp + 0 * NG * 64);
    // ---- layer 1 ----
    k_layer<true><<<nblk, 256, 0, stream>>>(yb, count, csr, b1_1,
                                            wT + 1 * 4096, b2_1, wT + 4 * 4096,
                                            ya, batch, gp + 1 * NG * 64);
    // ---- layer 2 ----
    k_layer<false><<<nblk, 256, 0, stream>>>(ya, count, csr, b1_2,
                                             wT + 2 * 4096, b2_2, nullptr,
                                             nullptr, batch, gp + 2 * NG * 64);

    // ---- head (pooled-JK + ffn + out; graph sizes via binary search) ----
    k_final<<<NG, 64, 0, stream>>>(gp, batch, jk_w, jk_b,
                                   ffn_w1, ffn_b1, bn_g, bn_b, bn_m, bn_v,
                                   ffn_w2, ffn_b2, out_w, out_b, (float*)d_out);
}